// Round 3
// baseline (771.105 us; speedup 1.0000x reference)
//
#include <hip/hip_runtime.h>
#include <math.h>

#define BB 8
#define CCH 32
#define HH 128
#define WW 128
#define OUTC 32
#define NPTS 16
#define NPIX (BB*HH*WW)          // 131072
#define HWP 131                   // Hp-1 = Wp-1 = 131

// workspace layout in floats
#define WS_XT 0                                  // B*H*W*C = 4194304 floats
#define WS_CONV4 (BB*HH*WW*CCH)                  // 4194304
#define WS_STATS (WS_CONV4 + BB*HH*WW*4)         // 8 floats: 4 sums, 4 sumsq
#define WS_BNAB  (WS_STATS + 8)                  // 8 floats: a[4], b[4]
#define WS_WK2   (WS_BNAB + 8)                   // 16384 floats, layout [n][c][o]

__constant__ float c_prfx[16] = {-2,-2,-2,-2, -2,-1, 0, 1,  2, 2, 2, 2, -1, 0, 1, 2};
__constant__ float c_prfy[16] = {-2,-1, 0, 1,  2, 2, 2, 2, -1, 0, 1, 2, -2,-2,-2,-2};

// ---------------- K1: transpose x (B,C,H,W) -> x_t (B,H,W,C); zero stats ---
__global__ __launch_bounds__(256) void k_transpose(const float* __restrict__ x,
                                                   float* __restrict__ ws) {
    __shared__ float tile[32][33];
    int blk = blockIdx.x;            // b*H*(W/32)
    int j0 = (blk & 3) << 5;
    int bi = blk >> 2;               // b*H + i
    int b = bi >> 7, i = bi & 127;
    int tx = threadIdx.x & 31;
    int ty = threadIdx.x >> 5;       // 0..7
    #pragma unroll
    for (int c = ty; c < 32; c += 8)
        tile[c][tx] = x[(((size_t)b*CCH + c)*HH + i)*WW + j0 + tx];
    __syncthreads();
    float* xt = ws + WS_XT;
    #pragma unroll
    for (int jj = ty; jj < 32; jj += 8)
        xt[(((size_t)bi)*WW + j0 + jj)*CCH + tx] = tile[tx][jj];
    if (blk == 0 && threadIdx.x < 8) ws[WS_STATS + threadIdx.x] = 0.f;
}

// ---------------- K2: 7-tap convs, 2 threads/pixel (h=0 vert, h=1 horz) ----
__global__ __launch_bounds__(256) void k_conv(float* __restrict__ ws,
        const float* __restrict__ w_vrt, const float* __restrict__ b_vrt,
        const float* __restrict__ w_hrz, const float* __restrict__ b_hrz) {
    const float* xt = ws + WS_XT;
    int p = threadIdx.x & 127;       // pixel within block
    int hgrp = threadIdx.x >> 7;     // 0: vertical conv, 1: horizontal conv
    int idx = blockIdx.x * 128 + p;
    int b = idx >> 14, ij = idx & 16383, i = ij >> 7, j = ij & 127;
    const float* xb = xt + (size_t)b * (HH*WW*CCH);
    const float* wgt = hgrp ? w_hrz : w_vrt;
    float a0 = 0.f, a1 = 0.f;
    for (int k = 0; k < 7; k++) {
        int r, cJ;
        if (hgrp == 0) { r = i + k - 3; cJ = j; if (r < 0 || r >= HH) continue; }
        else           { r = i; cJ = j + k - 3; if (cJ < 0 || cJ >= WW) continue; }
        const float4* pp = (const float4*)(xb + ((size_t)r*WW + cJ)*CCH);
        #pragma unroll
        for (int c4 = 0; c4 < 8; c4++) {
            float4 xv = pp[c4];
            int cb = c4 * 4;
            a0 += wgt[(cb+0)*7+k]*xv.x + wgt[(cb+1)*7+k]*xv.y
                + wgt[(cb+2)*7+k]*xv.z + wgt[(cb+3)*7+k]*xv.w;
            a1 += wgt[(32+cb+0)*7+k]*xv.x + wgt[(32+cb+1)*7+k]*xv.y
                + wgt[(32+cb+2)*7+k]*xv.z + wgt[(32+cb+3)*7+k]*xv.w;
        }
    }
    a0 += hgrp ? b_hrz[0] : b_vrt[0];
    a1 += hgrp ? b_hrz[1] : b_vrt[1];
    float2* conv2 = (float2*)(ws + WS_CONV4);
    conv2[idx * 2 + hgrp] = make_float2(a0, a1);
    // stats: waves 0,1 hold channels {0,1}; waves 2,3 hold {2,3}
    __shared__ float sw[4][4];
    float q[4] = {a0, a1, a0*a0, a1*a1};
    int lane = threadIdx.x & 63, wave = threadIdx.x >> 6;
    #pragma unroll
    for (int t = 0; t < 4; t++) {
        float s = q[t];
        for (int off = 32; off; off >>= 1) s += __shfl_down(s, off);
        if (lane == 0) sw[wave][t] = s;
    }
    __syncthreads();
    if (threadIdx.x < 8) {
        int t = threadIdx.x;
        int src  = (t & 2) ? 2 : 0;
        int comp = (t & 1) + ((t & 4) ? 2 : 0);
        atomicAdd(ws + WS_STATS + t, sw[src][comp] + sw[src+1][comp]);
    }
}

// ---------------- K3: BN affine consts + w_pk reorder to [n][c][o] ----------
__global__ void k_prep(const float* __restrict__ w_pk,
        const float* __restrict__ g_vrt, const float* __restrict__ be_vrt,
        const float* __restrict__ g_hrz, const float* __restrict__ be_hrz,
        float* __restrict__ ws) {
    float* wk2 = ws + WS_WK2;
    int e0 = blockIdx.x * 2048 + threadIdx.x;
    for (int e = e0; e < (blockIdx.x + 1) * 2048; e += 256) {
        int n = e >> 10, c = (e >> 5) & 31, o = e & 31;
        wk2[e] = w_pk[((o*32 + c) << 4) + n];
    }
    if (blockIdx.x == 0 && threadIdx.x < 4) {
        int t = threadIdx.x;
        const float cnt = (float)NPIX;
        float sum = ws[WS_STATS + t], sq = ws[WS_STATS + 4 + t];
        float mean = sum / cnt;
        float var  = sq / cnt - mean * mean;
        float gamma = (t < 2) ? g_vrt[t] : g_hrz[t - 2];
        float beta  = (t < 2) ? be_vrt[t] : be_hrz[t - 2];
        float a = gamma * rsqrtf(var + 1e-5f);
        ws[WS_BNAB + t]     = a;
        ws[WS_BNAB + 4 + t] = beta - mean * a;
    }
}

// ---------------- K4: deformable sample + matvec, 2 threads/pixel -----------
__global__ __launch_bounds__(256) void k_main(const float* __restrict__ ws,
        const float* __restrict__ b_pk, float* __restrict__ out) {
    const float* xt    = ws + WS_XT;
    const float* bnab  = ws + WS_BNAB;
    const float* wk2   = ws + WS_WK2;
    __shared__ float sred[128][33];
    int p = threadIdx.x & 127;       // pixel within block
    int hgrp = threadIdx.x >> 7;     // 0: n=0..7, 1: n=8..15
    int idx = blockIdx.x * 128 + p;
    int b = idx >> 14, ij = idx & 16383, i = ij >> 7, j = ij & 127;

    // center values x[b,:,i,j]
    float xc[32];
    const float4* xp = (const float4*)(xt + (size_t)idx * 32);
    #pragma unroll
    for (int c4 = 0; c4 < 8; c4++) {
        float4 v = xp[c4];
        xc[c4*4+0] = v.x; xc[c4*4+1] = v.y; xc[c4*4+2] = v.z; xc[c4*4+3] = v.w;
    }
    // gate values
    const float4* conv4 = (const float4*)(ws + WS_CONV4);
    float4 cv = conv4[idx];
    float gbv[4];
    gbv[0] = 2.f / (1.f + expf(-(cv.x * bnab[0] + bnab[4])));
    gbv[1] = 2.f / (1.f + expf(-(cv.y * bnab[1] + bnab[5])));
    gbv[2] = 2.f / (1.f + expf(-(cv.z * bnab[2] + bnab[6])));
    gbv[3] = 2.f / (1.f + expf(-(cv.w * bnab[3] + bnab[7])));

    float acc[32];
    #pragma unroll
    for (int o = 0; o < 32; o++) acc[o] = 0.f;

    const float* xb = xt + (size_t)b * (HH*WW*CCH);
    float fi = (float)i + 2.f, fj = (float)j + 2.f;

    #pragma unroll 1
    for (int nn = 0; nn < 8; nn++) {
        int n = hgrp * 8 + nn;
        float mx = 0.f, my = 0.f;
        if (n < 4)       mx = -gbv[0];
        else if (n < 8)  my =  gbv[3];
        else if (n < 12) mx =  gbv[1];
        else             my = -gbv[2];
        float px = fi + c_prfx[n] + mx;
        float py = fj + c_prfy[n] + my;
        float qlx = floorf(px), qly = floorf(py);
        int qlxi = min(max((int)qlx, 0), HWP);
        int qlyi = min(max((int)qly, 0), HWP);
        int qrxi = min(max((int)qlx + 1, 0), HWP);
        int qryi = min(max((int)qly + 1, 0), HWP);
        float pxc = fminf(fmaxf(px, 0.f), (float)HWP);
        float pyc = fminf(fmaxf(py, 0.f), (float)HWP);
        float glt = (1.f + ((float)qlxi - pxc)) * (1.f + ((float)qlyi - pyc));
        float grb = (1.f - ((float)qrxi - pxc)) * (1.f - ((float)qryi - pyc));
        // edge pad: x_pad[a] = x[clamp(a-2,0,127)]
        int ltr = min(max(qlxi - 2, 0), HH - 1), ltc = min(max(qlyi - 2, 0), WW - 1);
        int rbr = min(max(qrxi - 2, 0), HH - 1), rbc = min(max(qryi - 2, 0), WW - 1);
        const float4* plt = (const float4*)(xb + ((size_t)ltr * WW + ltc) * CCH);
        const float4* prb = (const float4*)(xb + ((size_t)rbr * WW + rbc) * CCH);
        const float* wn = wk2 + n * 1024;       // [c][o], o contiguous
        #pragma unroll
        for (int c4 = 0; c4 < 8; c4++) {
            float4 a = plt[c4], r = prb[c4];
            float d0 = xc[c4*4+0] - (glt * a.x + grb * r.x);
            float d1 = xc[c4*4+1] - (glt * a.y + grb * r.y);
            float d2 = xc[c4*4+2] - (glt * a.z + grb * r.z);
            float d3 = xc[c4*4+3] - (glt * a.w + grb * r.w);
            const float* w0 = wn + c4 * 128;
            #pragma unroll
            for (int o = 0; o < 32; o++) {
                acc[o] += w0[o] * d0 + w0[32+o] * d1 + w0[64+o] * d2 + w0[96+o] * d3;
            }
        }
    }
    // combine halves: h=1 deposits, h=0 adds + stores
    if (hgrp == 1) {
        #pragma unroll
        for (int o = 0; o < 32; o++) sred[p][o] = acc[o];
    }
    __syncthreads();
    if (hgrp == 0) {
        float* op = out + (size_t)b * (OUTC*HH*WW) + ij;
        #pragma unroll
        for (int o = 0; o < 32; o++)
            op[(size_t)o * (HH*WW)] = acc[o] + sred[p][o] + b_pk[o];
    }
}

extern "C" void kernel_launch(void* const* d_in, const int* in_sizes, int n_in,
                              void* d_out, int out_size, void* d_ws, size_t ws_size,
                              hipStream_t stream) {
    const float* x      = (const float*)d_in[0];
    const float* w_vrt  = (const float*)d_in[1];
    const float* b_vrt  = (const float*)d_in[2];
    const float* g_vrt  = (const float*)d_in[3];
    const float* be_vrt = (const float*)d_in[4];
    const float* w_hrz  = (const float*)d_in[5];
    const float* b_hrz  = (const float*)d_in[6];
    const float* g_hrz  = (const float*)d_in[7];
    const float* be_hrz = (const float*)d_in[8];
    const float* w_pk   = (const float*)d_in[9];
    const float* b_pk   = (const float*)d_in[10];
    float* ws  = (float*)d_ws;
    float* out = (float*)d_out;

    k_transpose<<<BB*HH*(WW/32), 256, 0, stream>>>(x, ws);
    k_conv<<<NPIX/128, 256, 0, stream>>>(ws, w_vrt, b_vrt, w_hrz, b_hrz);
    k_prep<<<8, 256, 0, stream>>>(w_pk, g_vrt, be_vrt, g_hrz, be_hrz, ws);
    k_main<<<NPIX/128, 256, 0, stream>>>(ws, b_pk, out);
}

// Round 4
// 246.286 us; speedup vs baseline: 3.1309x; 3.1309x over previous
//
#include <hip/hip_runtime.h>
#include <math.h>

#define BB 8
#define CCH 32
#define HH 128
#define WW 128
#define OUTC 32
#define NPTS 16
#define NPIX (BB*HH*WW)          // 131072
#define HWP 131                   // Hp-1 = Wp-1 = 131

// workspace layout in floats
#define WS_XT 0                                  // B*H*W*C = 4194304 floats
#define WS_CONV4 (BB*HH*WW*CCH)                  // pre-BN conv outputs, 4 f/pixel
#define WS_STATS (WS_CONV4 + BB*HH*WW*4)         // 8 floats: 4 sums, 4 sumsq
#define WS_BNAB  (WS_STATS + 8)                  // 8 floats: a[4], b[4]
#define WS_WKB   (WS_BNAB + 8)                   // 16384 ushorts (8192 floats): bf16 W[o][k], k=n*32+c

#define DROW 136                                  // padded d-row length in ushorts (128 + 8)

typedef __attribute__((ext_vector_type(8))) short short8;
typedef __attribute__((ext_vector_type(4))) float f32x4;

__constant__ float c_prfx[16] = {-2,-2,-2,-2, -2,-1, 0, 1,  2, 2, 2, 2, -1, 0, 1, 2};
__constant__ float c_prfy[16] = {-2,-1, 0, 1,  2, 2, 2, 2, -1, 0, 1, 2, -2,-2,-2,-2};

__device__ __forceinline__ unsigned short f2bf(float f) {
    unsigned u = __float_as_uint(f);
    unsigned r = (u + 0x7FFFu + ((u >> 16) & 1u)) >> 16;   // RTNE
    return (unsigned short)r;
}

// ---------------- K1: transpose x (B,C,H,W) -> x_t (B,H,W,C); zero stats ---
__global__ __launch_bounds__(256) void k_transpose(const float* __restrict__ x,
                                                   float* __restrict__ ws) {
    __shared__ float tile[32][33];
    int blk = blockIdx.x;            // b*H*(W/32)
    int j0 = (blk & 3) << 5;
    int bi = blk >> 2;               // b*H + i
    int b = bi >> 7, i = bi & 127;
    int tx = threadIdx.x & 31;
    int ty = threadIdx.x >> 5;       // 0..7
    #pragma unroll
    for (int c = ty; c < 32; c += 8)
        tile[c][tx] = x[(((size_t)b*CCH + c)*HH + i)*WW + j0 + tx];
    __syncthreads();
    float* xt = ws + WS_XT;
    #pragma unroll
    for (int jj = ty; jj < 32; jj += 8)
        xt[(((size_t)bi)*WW + j0 + jj)*CCH + tx] = tile[tx][jj];
    if (blk == 0 && threadIdx.x < 8) ws[WS_STATS + threadIdx.x] = 0.f;
}

// ---------------- conv core: weight ptr must be call-site literal (uniform) --
__device__ __forceinline__ void conv_core(const float* __restrict__ xb, int i, int j,
        int vert, const float* __restrict__ wgt, const float* __restrict__ bias,
        float& a0, float& a1) {
    a0 = 0.f; a1 = 0.f;
    for (int k = 0; k < 7; k++) {
        int r  = vert ? (i + k - 3) : i;
        int cJ = vert ? j : (j + k - 3);
        int lim = vert ? r : cJ;
        if (lim < 0 || lim >= 128) continue;
        const float4* pp = (const float4*)(xb + ((size_t)r*WW + cJ)*CCH);
        #pragma unroll
        for (int c4 = 0; c4 < 8; c4++) {
            float4 xv = pp[c4];
            int cb = c4 * 4;
            a0 += wgt[(cb+0)*7+k]*xv.x + wgt[(cb+1)*7+k]*xv.y
                + wgt[(cb+2)*7+k]*xv.z + wgt[(cb+3)*7+k]*xv.w;
            a1 += wgt[(224+(cb+0)*7)+k]*xv.x + wgt[(224+(cb+1)*7)+k]*xv.y
                + wgt[(224+(cb+2)*7)+k]*xv.z + wgt[(224+(cb+3)*7)+k]*xv.w;
        }
    }
    a0 += bias[0]; a1 += bias[1];
}

// ---------------- K2: 7-tap convs, 2 threads/pixel (h=0 vert, h=1 horz) ----
__global__ __launch_bounds__(256) void k_conv(float* __restrict__ ws,
        const float* __restrict__ w_vrt, const float* __restrict__ b_vrt,
        const float* __restrict__ w_hrz, const float* __restrict__ b_hrz) {
    const float* xt = ws + WS_XT;
    int p = threadIdx.x & 127;       // pixel within block
    int hgrp = threadIdx.x >> 7;     // 0: vertical conv, 1: horizontal conv
    int idx = blockIdx.x * 128 + p;
    int b = idx >> 14, ij = idx & 16383, i = ij >> 7, j = ij & 127;
    const float* xb = xt + (size_t)b * (HH*WW*CCH);
    float a0, a1;
    if (hgrp == 0) conv_core(xb, i, j, 1, w_vrt, b_vrt, a0, a1);   // uniform ptr
    else           conv_core(xb, i, j, 0, w_hrz, b_hrz, a0, a1);   // uniform ptr
    float2* conv2 = (float2*)(ws + WS_CONV4);
    conv2[idx * 2 + hgrp] = make_float2(a0, a1);
    // stats: waves 0,1 hold channels {0,1}; waves 2,3 hold {2,3}
    __shared__ float sw[4][4];
    float q[4] = {a0, a1, a0*a0, a1*a1};
    int lane = threadIdx.x & 63, wave = threadIdx.x >> 6;
    #pragma unroll
    for (int t = 0; t < 4; t++) {
        float s = q[t];
        for (int off = 32; off; off >>= 1) s += __shfl_down(s, off);
        if (lane == 0) sw[wave][t] = s;
    }
    __syncthreads();
    if (threadIdx.x < 8) {
        int t = threadIdx.x;
        int src  = (t & 2) ? 2 : 0;
        int comp = (t & 1) + ((t & 4) ? 2 : 0);
        atomicAdd(ws + WS_STATS + t, sw[src][comp] + sw[src+1][comp]);
    }
}

// ---------------- K3: BN affine consts + bf16 weight table W[o][k], k=n*32+c
__global__ void k_prep(const float* __restrict__ w_pk,
        const float* __restrict__ g_vrt, const float* __restrict__ be_vrt,
        const float* __restrict__ g_hrz, const float* __restrict__ be_hrz,
        float* __restrict__ ws) {
    unsigned short* wkb = (unsigned short*)(ws + WS_WKB);
    int e0 = blockIdx.x * 2048 + threadIdx.x;
    for (int e = e0; e < (blockIdx.x + 1) * 2048; e += 256) {
        int o = e >> 9, n = (e >> 5) & 15, c = e & 31;
        wkb[o*512 + n*32 + c] = f2bf(w_pk[((o*32 + c) << 4) + n]);
    }
    if (blockIdx.x == 0 && threadIdx.x < 4) {
        int t = threadIdx.x;
        const float cnt = (float)NPIX;
        float sum = ws[WS_STATS + t], sq = ws[WS_STATS + 4 + t];
        float mean = sum / cnt;
        float var  = sq / cnt - mean * mean;
        float gamma = (t < 2) ? g_vrt[t] : g_hrz[t - 2];
        float beta  = (t < 2) ? be_vrt[t] : be_hrz[t - 2];
        float a = gamma * rsqrtf(var + 1e-5f);
        ws[WS_BNAB + t]     = a;
        ws[WS_BNAB + 4 + t] = beta - mean * a;
    }
}

// ---------------- K4: gather+interp -> bf16 d in LDS -> MFMA GEMM -----------
// block = 256 thr = 64 pixels. K=512 split into 4 chunks of 128 (4 ring pts).
// Phase A: thread (pix=t&63, n=cc*4+(t>>6)) computes d[pix][n*32..+31] -> LDS.
// Phase B: wave w does pixels w*16..w*16+15: D[32 x 16] via 16x16x32 bf16 MFMA.
__global__ __launch_bounds__(256) void k_main(const float* __restrict__ ws,
        const float* __restrict__ b_pk, float* __restrict__ out) {
    const float* xt   = ws + WS_XT;
    const float* bnab = ws + WS_BNAB;
    const unsigned short* wkb = (const unsigned short*)(ws + WS_WKB);
    __shared__ unsigned short dlds[64 * DROW];    // 17408 B

    int t = threadIdx.x;
    int p = t & 63;                  // pixel (phase A)
    int w = t >> 6;                  // wave id
    int idx = blockIdx.x * 64 + p;
    int b = idx >> 14, ij = idx & 16383, i = ij >> 7, j = ij & 127;
    const float* xb = xt + (size_t)b * (HH*WW*CCH);

    // center values for my pixel
    float xc[32];
    const float4* xp = (const float4*)(xt + (size_t)idx * 32);
    #pragma unroll
    for (int c4 = 0; c4 < 8; c4++) {
        float4 v = xp[c4];
        xc[c4*4+0] = v.x; xc[c4*4+1] = v.y; xc[c4*4+2] = v.z; xc[c4*4+3] = v.w;
    }
    // gates for my pixel
    const float4* conv4 = (const float4*)(ws + WS_CONV4);
    float4 cv = conv4[idx];
    float gbv[4];
    gbv[0] = 2.f / (1.f + expf(-(cv.x * bnab[0] + bnab[4])));
    gbv[1] = 2.f / (1.f + expf(-(cv.y * bnab[1] + bnab[5])));
    gbv[2] = 2.f / (1.f + expf(-(cv.z * bnab[2] + bnab[6])));
    gbv[3] = 2.f / (1.f + expf(-(cv.w * bnab[3] + bnab[7])));

    f32x4 acc0 = {0.f,0.f,0.f,0.f}, acc1 = {0.f,0.f,0.f,0.f};
    int pl = t & 15, quad = (t >> 4) & 3;
    float fi = (float)i + 2.f, fj = (float)j + 2.f;

    for (int cc = 0; cc < 4; cc++) {
        // ---- phase A: my (pixel, n) slice of d
        int n = cc * 4 + w;
        float mx = 0.f, my = 0.f;
        if (n < 4)       mx = -gbv[0];
        else if (n < 8)  my =  gbv[3];
        else if (n < 12) mx =  gbv[1];
        else             my = -gbv[2];
        float px = fi + c_prfx[n] + mx;
        float py = fj + c_prfy[n] + my;
        float qlx = floorf(px), qly = floorf(py);
        int qlxi = min(max((int)qlx, 0), HWP);
        int qlyi = min(max((int)qly, 0), HWP);
        int qrxi = min(max((int)qlx + 1, 0), HWP);
        int qryi = min(max((int)qly + 1, 0), HWP);
        float pxc = fminf(fmaxf(px, 0.f), (float)HWP);
        float pyc = fminf(fmaxf(py, 0.f), (float)HWP);
        float glt = (1.f + ((float)qlxi - pxc)) * (1.f + ((float)qlyi - pyc));
        float grb = (1.f - ((float)qrxi - pxc)) * (1.f - ((float)qryi - pyc));
        int ltr = min(max(qlxi - 2, 0), HH - 1), ltc = min(max(qlyi - 2, 0), WW - 1);
        int rbr = min(max(qrxi - 2, 0), HH - 1), rbc = min(max(qryi - 2, 0), WW - 1);
        const float4* plt = (const float4*)(xb + ((size_t)ltr * WW + ltc) * CCH);
        const float4* prb = (const float4*)(xb + ((size_t)rbr * WW + rbc) * CCH);
        unsigned short* drow = dlds + p * DROW + w * 32;
        #pragma unroll
        for (int c4 = 0; c4 < 8; c4++) {
            float4 a = plt[c4], r = prb[c4];
            float d0 = xc[c4*4+0] - (glt * a.x + grb * r.x);
            float d1 = xc[c4*4+1] - (glt * a.y + grb * r.y);
            float d2 = xc[c4*4+2] - (glt * a.z + grb * r.z);
            float d3 = xc[c4*4+3] - (glt * a.w + grb * r.w);
            unsigned u0 = (unsigned)f2bf(d0) | ((unsigned)f2bf(d1) << 16);
            unsigned u1 = (unsigned)f2bf(d2) | ((unsigned)f2bf(d3) << 16);
            *(uint2*)(drow + c4 * 4) = make_uint2(u0, u1);
        }
        __syncthreads();
        // ---- phase B: MFMA over this chunk (K=128 -> 4 k-tiles of 32)
        const unsigned short* brow = dlds + (w * 16 + pl) * DROW;
        #pragma unroll
        for (int kt = 0; kt < 4; kt++) {
            short8 bf = *(const short8*)(brow + kt * 32 + quad * 8);
            int kg = cc * 128 + kt * 32 + quad * 8;
            short8 a0 = *(const short8*)(wkb + (size_t)pl * 512 + kg);
            short8 a1 = *(const short8*)(wkb + (size_t)(pl + 16) * 512 + kg);
            acc0 = __builtin_amdgcn_mfma_f32_16x16x32_bf16(a0, bf, acc0, 0, 0, 0);
            acc1 = __builtin_amdgcn_mfma_f32_16x16x32_bf16(a1, bf, acc1, 0, 0, 0);
        }
        __syncthreads();
    }
    // ---- epilogue: D col = lane&15 (pixel), row = quad*4+reg (out channel)
    int pix = blockIdx.x * 64 + w * 16 + pl;
    int ob = pix >> 14, oij = pix & 16383;
    float* op = out + (size_t)ob * (OUTC * HH * WW) + oij;
    #pragma unroll
    for (int r = 0; r < 4; r++) {
        int o0 = quad * 4 + r;
        op[(size_t)o0 * (HH*WW)]        = acc0[r] + b_pk[o0];
        op[(size_t)(o0 + 16) * (HH*WW)] = acc1[r] + b_pk[o0 + 16];
    }
}

extern "C" void kernel_launch(void* const* d_in, const int* in_sizes, int n_in,
                              void* d_out, int out_size, void* d_ws, size_t ws_size,
                              hipStream_t stream) {
    const float* x      = (const float*)d_in[0];
    const float* w_vrt  = (const float*)d_in[1];
    const float* b_vrt  = (const float*)d_in[2];
    const float* g_vrt  = (const float*)d_in[3];
    const float* be_vrt = (const float*)d_in[4];
    const float* w_hrz  = (const float*)d_in[5];
    const float* b_hrz  = (const float*)d_in[6];
    const float* g_hrz  = (const float*)d_in[7];
    const float* be_hrz = (const float*)d_in[8];
    const float* w_pk   = (const float*)d_in[9];
    const float* b_pk   = (const float*)d_in[10];
    float* ws  = (float*)d_ws;
    float* out = (float*)d_out;

    k_transpose<<<BB*HH*(WW/32), 256, 0, stream>>>(x, ws);
    k_conv<<<NPIX/128, 256, 0, stream>>>(ws, w_vrt, b_vrt, w_hrz, b_hrz);
    k_prep<<<8, 256, 0, stream>>>(w_pk, g_vrt, be_vrt, g_hrz, be_hrz, ws);
    k_main<<<NPIX/64, 256, 0, stream>>>(ws, b_pk, out);
}

// Round 7
// 177.666 us; speedup vs baseline: 4.3402x; 1.3862x over previous
//
#include <hip/hip_runtime.h>
#include <math.h>

#define BB 8
#define CCH 32
#define HH 128
#define WW 128
#define OUTC 32
#define NPIX (BB*HH*WW)          // 131072
#define HWP 131                   // padded-coord clamp limit

// workspace layout (float offsets) — total 18.90 MB
#define WS_XT    0                                   // fp32 x_t [b][i][j][c], 16 MB
#define WS_CONV4 (BB*HH*WW*CCH)                      // pre-BN conv, 4 f/px, 2 MB
#define WS_STATS (WS_CONV4 + BB*HH*WW*4)             // 8 f
#define WS_BNAB  (WS_STATS + 8)                      // 8 f
#define WS_WKB   (WS_BNAB + 8)                       // 16384 ushort bf16 W[o][k], k=n*32+c

typedef __attribute__((ext_vector_type(8))) short short8;
typedef __attribute__((ext_vector_type(4))) float f32x4;

__device__ __forceinline__ unsigned short f2bf(float f) {
    unsigned u = __float_as_uint(f);
    unsigned r = (u + 0x7FFFu + ((u >> 16) & 1u)) >> 16;   // RTNE
    return (unsigned short)r;
}
__device__ __forceinline__ unsigned pk2(float a, float b) {
    return (unsigned)f2bf(a) | ((unsigned)f2bf(b) << 16);
}
__device__ __forceinline__ float bflo(unsigned w) { return __uint_as_float(w << 16); }
__device__ __forceinline__ float bfhi(unsigned w) { return __uint_as_float(w & 0xFFFF0000u); }

// ---------------- K1: transpose x (B,C,H,W) -> x_t fp32 [b][i][j][c] -------
__global__ __launch_bounds__(256) void k_transpose(const float* __restrict__ x,
                                                   float* __restrict__ ws) {
    __shared__ float tile[32][33];
    int blk = blockIdx.x;            // b*H*(W/32)
    int j0 = (blk & 3) << 5;
    int bi = blk >> 2;               // b*H + i
    int b = bi >> 7, i = bi & 127;
    int tx = threadIdx.x & 31;
    int ty = threadIdx.x >> 5;       // 0..7
    #pragma unroll
    for (int c = ty; c < 32; c += 8)
        tile[c][tx] = x[(((size_t)b*CCH + c)*HH + i)*WW + j0 + tx];
    __syncthreads();
    float* xt = ws + WS_XT;
    #pragma unroll
    for (int jj = ty; jj < 32; jj += 8)
        xt[(((size_t)bi)*WW + j0 + jj)*CCH + tx] = tile[tx][jj];
    if (blk == 0 && threadIdx.x < 8) ws[WS_STATS + threadIdx.x] = 0.f;
}

// ---------------- K2: R2-EXACT proven version — 1 thr/px, global fp32 ------
__global__ __launch_bounds__(256) void k_conv(float* __restrict__ ws,
        const float* __restrict__ w_vrt, const float* __restrict__ b_vrt,
        const float* __restrict__ w_hrz, const float* __restrict__ b_hrz) {
    const float* xt = ws + WS_XT;
    int idx = blockIdx.x * 256 + threadIdx.x;
    int b = idx >> 14, ij = idx & 16383, i = ij >> 7, j = ij & 127;
    const float* xb = xt + (size_t)b * (HH*WW*CCH);
    float v0 = 0.f, v1 = 0.f, h0 = 0.f, h1 = 0.f;
    // vertical conv: kernel (2,C,7,1), zero pad 3 in H
    for (int k = 0; k < 7; k++) {
        int r = i + k - 3;
        if (r < 0 || r >= HH) continue;
        const float4* p = (const float4*)(xb + ((size_t)r*WW + j)*CCH);
        #pragma unroll
        for (int c4 = 0; c4 < 8; c4++) {
            float4 xv = p[c4];
            int cb = c4 * 4;
            v0 += w_vrt[(cb+0)*7+k]*xv.x + w_vrt[(cb+1)*7+k]*xv.y
                + w_vrt[(cb+2)*7+k]*xv.z + w_vrt[(cb+3)*7+k]*xv.w;
            v1 += w_vrt[(32+cb+0)*7+k]*xv.x + w_vrt[(32+cb+1)*7+k]*xv.y
                + w_vrt[(32+cb+2)*7+k]*xv.z + w_vrt[(32+cb+3)*7+k]*xv.w;
        }
    }
    // horizontal conv: kernel (2,C,1,7), zero pad 3 in W
    for (int k = 0; k < 7; k++) {
        int cJ = j + k - 3;
        if (cJ < 0 || cJ >= WW) continue;
        const float4* p = (const float4*)(xb + ((size_t)i*WW + cJ)*CCH);
        #pragma unroll
        for (int c4 = 0; c4 < 8; c4++) {
            float4 xv = p[c4];
            int cb = c4 * 4;
            h0 += w_hrz[(cb+0)*7+k]*xv.x + w_hrz[(cb+1)*7+k]*xv.y
                + w_hrz[(cb+2)*7+k]*xv.z + w_hrz[(cb+3)*7+k]*xv.w;
            h1 += w_hrz[(32+cb+0)*7+k]*xv.x + w_hrz[(32+cb+1)*7+k]*xv.y
                + w_hrz[(32+cb+2)*7+k]*xv.z + w_hrz[(32+cb+3)*7+k]*xv.w;
        }
    }
    v0 += b_vrt[0]; v1 += b_vrt[1]; h0 += b_hrz[0]; h1 += b_hrz[1];
    float4* conv4 = (float4*)(ws + WS_CONV4);
    conv4[idx] = make_float4(v0, v1, h0, h1);
    // block reduction of sum + sumsq for 4 channels
    __shared__ float sred[4][8];
    float q[8] = {v0, v1, h0, h1, v0*v0, v1*v1, h0*h0, h1*h1};
    int lane = threadIdx.x & 63, wave = threadIdx.x >> 6;
    #pragma unroll
    for (int t = 0; t < 8; t++) {
        float s = q[t];
        for (int off = 32; off; off >>= 1) s += __shfl_down(s, off);
        if (lane == 0) sred[wave][t] = s;
    }
    __syncthreads();
    if (threadIdx.x < 8) {
        float s = sred[0][threadIdx.x] + sred[1][threadIdx.x]
                + sred[2][threadIdx.x] + sred[3][threadIdx.x];
        atomicAdd(ws + WS_STATS + threadIdx.x, s);
    }
}

// ---------------- K3: BN affine consts + bf16 weight table W[o][k] ----------
__global__ void k_prep(const float* __restrict__ w_pk,
        const float* __restrict__ g_vrt, const float* __restrict__ be_vrt,
        const float* __restrict__ g_hrz, const float* __restrict__ be_hrz,
        float* __restrict__ ws) {
    unsigned short* wkb = (unsigned short*)(ws + WS_WKB);
    int e0 = blockIdx.x * 2048 + threadIdx.x;
    for (int e = e0; e < (blockIdx.x + 1) * 2048; e += 256) {
        int o = e >> 9, n = (e >> 5) & 15, c = e & 31;
        wkb[o*512 + n*32 + c] = f2bf(w_pk[((o*32 + c) << 4) + n]);
    }
    if (blockIdx.x == 0 && threadIdx.x < 4) {
        int t = threadIdx.x;
        const float cnt = (float)NPIX;
        float sum = ws[WS_STATS + t], sq = ws[WS_STATS + 4 + t];
        float mean = sum / cnt;
        float var  = sq / cnt - mean * mean;
        float gamma = (t < 2) ? g_vrt[t] : g_hrz[t - 2];
        float beta  = (t < 2) ? be_vrt[t] : be_hrz[t - 2];
        float a = gamma * rsqrtf(var + 1e-5f);
        ws[WS_BNAB + t]     = a;
        ws[WS_BNAB + 4 + t] = beta - mean * a;
    }
}

// ---------------- K4: LDS-tiled gather + interp + MFMA (R6 version) ---------
__global__ __launch_bounds__(256) void k_main(const float* __restrict__ ws,
        const float* __restrict__ b_pk, float* __restrict__ out) {
    __shared__ unsigned short tile[4*9*72*8];     // 41472 B
    const float* xt   = ws + WS_XT;
    const float* bnab = ws + WS_BNAB;
    const unsigned short* wkb = (const unsigned short*)(ws + WS_WKB);
    const float prfx[16] = {-2,-2,-2,-2, -2,-1, 0, 1,  2, 2, 2, 2, -1, 0, 1, 2};
    const float prfy[16] = {-2,-1, 0, 1,  2, 2, 2, 2, -1, 0, 1, 2, -2,-2,-2,-2};

    int t = threadIdx.x;
    int idx0 = blockIdx.x * 64;
    int b = idx0 >> 14, ij0 = idx0 & 16383, i = ij0 >> 7, j0 = ij0 & 127;

    // ---- coalesced tile load (fp32 -> bf16, edge clamp)
    for (int s = t; s < 9*72*4; s += 256) {
        int q = s & 3, cc = (s >> 2) % 72, r = (s >> 2) / 72;
        int gr = min(max(i - 4 + r, 0), HH - 1);
        int gc = min(max(j0 - 4 + cc, 0), WW - 1);
        const float4* src = (const float4*)(xt + (((size_t)(b*HH + gr))*WW + gc)*CCH + q*8);
        float4 f0 = src[0], f1 = src[1];
        uint4 v;
        v.x = pk2(f0.x, f0.y); v.y = pk2(f0.z, f0.w);
        v.z = pk2(f1.x, f1.y); v.w = pk2(f1.z, f1.w);
        *(uint4*)(tile + (((q*9 + r)*72 + cc)*8)) = v;
    }
    __syncthreads();

    int w = t >> 6, pl = t & 15, quad = (t >> 4) & 3;
    int pix = idx0 + w*16 + pl;
    int pj = j0 + w*16 + pl;

    // my 8 fp32 center channels (coalesced)
    float xc8[8];
    {
        const float4* xp = (const float4*)(xt + (size_t)pix * CCH + quad * 8);
        float4 v0 = xp[0], v1 = xp[1];
        xc8[0]=v0.x; xc8[1]=v0.y; xc8[2]=v0.z; xc8[3]=v0.w;
        xc8[4]=v1.x; xc8[5]=v1.y; xc8[6]=v1.z; xc8[7]=v1.w;
    }
    // gates for my pixel (identical across quads)
    const float4* conv4 = (const float4*)(ws + WS_CONV4);
    float4 cv = conv4[pix];
    float gbv[4];
    gbv[0] = 2.f / (1.f + expf(-(cv.x * bnab[0] + bnab[4])));
    gbv[1] = 2.f / (1.f + expf(-(cv.y * bnab[1] + bnab[5])));
    gbv[2] = 2.f / (1.f + expf(-(cv.z * bnab[2] + bnab[6])));
    gbv[3] = 2.f / (1.f + expf(-(cv.w * bnab[3] + bnab[7])));

    f32x4 acc0 = {0.f,0.f,0.f,0.f}, acc1 = {0.f,0.f,0.f,0.f};
    float fi = (float)i + 2.f, fj = (float)pj + 2.f;

    #pragma unroll
    for (int n = 0; n < 16; n++) {
        float mx = 0.f, my = 0.f;
        if (n < 4)       mx = -gbv[0];
        else if (n < 8)  my =  gbv[3];
        else if (n < 12) mx =  gbv[1];
        else             my = -gbv[2];
        float px = fi + prfx[n] + mx;
        float py = fj + prfy[n] + my;
        float qlx = floorf(px), qly = floorf(py);
        int qlxi = min(max((int)qlx, 0), HWP);
        int qlyi = min(max((int)qly, 0), HWP);
        int qrxi = min(max((int)qlx + 1, 0), HWP);
        int qryi = min(max((int)qly + 1, 0), HWP);
        float pxc = fminf(fmaxf(px, 0.f), (float)HWP);
        float pyc = fminf(fmaxf(py, 0.f), (float)HWP);
        float glt = (1.f + ((float)qlxi - pxc)) * (1.f + ((float)qlyi - pyc));
        float grb = (1.f - ((float)qrxi - pxc)) * (1.f - ((float)qryi - pyc));
        // edge pad: x_pad[a] = x[clamp(a-2,0,127)]
        int ltr = min(max(qlxi - 2, 0), HH - 1), ltc = min(max(qlyi - 2, 0), WW - 1);
        int rbr = min(max(qrxi - 2, 0), HH - 1), rbc = min(max(qryi - 2, 0), WW - 1);
        // tile-local coords
        int lt_off = ((quad*9 + (ltr - i + 4))*72 + (ltc - j0 + 4)) * 8;
        int rb_off = ((quad*9 + (rbr - i + 4))*72 + (rbc - j0 + 4)) * 8;
        uint4 lw = *(const uint4*)(tile + lt_off);
        uint4 rw = *(const uint4*)(tile + rb_off);
        float d0 = xc8[0] - (glt*bflo(lw.x) + grb*bflo(rw.x));
        float d1 = xc8[1] - (glt*bfhi(lw.x) + grb*bfhi(rw.x));
        float d2 = xc8[2] - (glt*bflo(lw.y) + grb*bflo(rw.y));
        float d3 = xc8[3] - (glt*bfhi(lw.y) + grb*bfhi(rw.y));
        float d4 = xc8[4] - (glt*bflo(lw.z) + grb*bflo(rw.z));
        float d5 = xc8[5] - (glt*bfhi(lw.z) + grb*bfhi(rw.z));
        float d6 = xc8[6] - (glt*bflo(lw.w) + grb*bflo(rw.w));
        float d7 = xc8[7] - (glt*bfhi(lw.w) + grb*bfhi(rw.w));
        uint4 bw;
        bw.x = pk2(d0, d1); bw.y = pk2(d2, d3);
        bw.z = pk2(d4, d5); bw.w = pk2(d6, d7);
        short8 bfrag = *(short8*)&bw;
        // A-frags: W rows pl and pl+16, k = n*32 + quad*8 .. +7 (L1-hot)
        short8 a0 = *(const short8*)(wkb + (size_t)pl * 512 + n*32 + quad*8);
        short8 a1 = *(const short8*)(wkb + (size_t)(pl + 16) * 512 + n*32 + quad*8);
        acc0 = __builtin_amdgcn_mfma_f32_16x16x32_bf16(a0, bfrag, acc0, 0, 0, 0);
        acc1 = __builtin_amdgcn_mfma_f32_16x16x32_bf16(a1, bfrag, acc1, 0, 0, 0);
    }
    // epilogue: col = pl (pixel), row = quad*4+reg (out channel)
    int pb = pix >> 14, pij = pix & 16383;
    float* op = out + (size_t)pb * (OUTC*HH*WW) + pij;
    #pragma unroll
    for (int r = 0; r < 4; r++) {
        int o = quad*4 + r;
        op[(size_t)o * (HH*WW)]        = acc0[r] + b_pk[o];
        op[(size_t)(o + 16) * (HH*WW)] = acc1[r] + b_pk[o + 16];
    }
}

extern "C" void kernel_launch(void* const* d_in, const int* in_sizes, int n_in,
                              void* d_out, int out_size, void* d_ws, size_t ws_size,
                              hipStream_t stream) {
    const float* x      = (const float*)d_in[0];
    const float* w_vrt  = (const float*)d_in[1];
    const float* b_vrt  = (const float*)d_in[2];
    const float* g_vrt  = (const float*)d_in[3];
    const float* be_vrt = (const float*)d_in[4];
    const float* w_hrz  = (const float*)d_in[5];
    const float* b_hrz  = (const float*)d_in[6];
    const float* g_hrz  = (const float*)d_in[7];
    const float* be_hrz = (const float*)d_in[8];
    const float* w_pk   = (const float*)d_in[9];
    const float* b_pk   = (const float*)d_in[10];
    float* ws  = (float*)d_ws;
    float* out = (float*)d_out;

    k_transpose<<<BB*HH*(WW/32), 256, 0, stream>>>(x, ws);
    k_conv<<<NPIX/256, 256, 0, stream>>>(ws, w_vrt, b_vrt, w_hrz, b_hrz);
    k_prep<<<8, 256, 0, stream>>>(w_pk, g_vrt, be_vrt, g_hrz, be_hrz, ws);
    k_main<<<NPIX/64, 256, 0, stream>>>(ws, b_pk, out);
}